// Round 7
// baseline (412.463 us; speedup 1.0000x reference)
//
#include <hip/hip_runtime.h>

#define NTOK 65536
#define DIM 256
#define KC 1024
#define EPS 0.08f

typedef __attribute__((ext_vector_type(8))) _Float16 f16x8;
typedef __attribute__((ext_vector_type(8))) unsigned short u16x8;
typedef __attribute__((ext_vector_type(4))) float f32x4;

static __device__ __forceinline__ unsigned short f16bits(float f) {
  _Float16 h = (_Float16)f;
  return __builtin_bit_cast(unsigned short, h);
}

// ---- e: fp32 -> fp16 FRAGMENT-MAJOR global image + esq; zero scalars ----
// Chunk c = ct*64 + s*8 + nj (1 KB each): lane = kq*16+col holds
// e[ct*128 + nj*16 + col][s*32 + kq*8 + j], j=0..7, as 8 f16.
__global__ __launch_bounds__(256) void vq_prep_e(const float* __restrict__ e,
                                                 unsigned short* __restrict__ eg,
                                                 float* __restrict__ esq,
                                                 int* __restrict__ hist,
                                                 int* __restrict__ fixCount,
                                                 float* __restrict__ lossCorr) {
  const int gid = blockIdx.x * 256 + threadIdx.x;  // 32768 work items
  const int t = gid >> 5;   // code row 0..1023
  const int o = gid & 31;   // k-octet 0..31
  const float4 v0 = *reinterpret_cast<const float4*>(&e[t * DIM + o * 8]);
  const float4 v1 = *reinterpret_cast<const float4*>(&e[t * DIM + o * 8 + 4]);
  u16x8 u;
  u[0] = f16bits(v0.x); u[1] = f16bits(v0.y); u[2] = f16bits(v0.z); u[3] = f16bits(v0.w);
  u[4] = f16bits(v1.x); u[5] = f16bits(v1.y); u[6] = f16bits(v1.z); u[7] = f16bits(v1.w);
  const int ct = t >> 7, nj = (t >> 4) & 7, col = t & 15;
  const int s = o >> 2, kq = o & 3;
  char* dst = (char*)eg + ((ct * 64 + s * 8 + nj) << 10) + ((kq * 16 + col) << 4);
  *reinterpret_cast<u16x8*>(dst) = u;
  float p = v0.x * v0.x + v0.y * v0.y + v0.z * v0.z + v0.w * v0.w +
            v1.x * v1.x + v1.y * v1.y + v1.z * v1.z + v1.w * v1.w;
#pragma unroll
  for (int m = 16; m > 0; m >>= 1) p += __shfl_xor(p, m, 64);
  if (o == 0) esq[t] = p;
  if (blockIdx.x < 4) hist[blockIdx.x * 256 + threadIdx.x] = 0;
  if (gid == 0) { *fixCount = 0; *lossCorr = 0.f; }
}

// ---- half-codebook argmin: 128 tokens x 512 codes per block ----
__global__ __launch_bounds__(256, 4) void vq_argmin(
    const float* __restrict__ x, const unsigned short* __restrict__ eg,
    const float* __restrict__ esq, float* __restrict__ bH,
    unsigned int* __restrict__ iH, float* __restrict__ xsq) {
  const int tid = threadIdx.x, lane = tid & 63, w = tid >> 6;
  const int tb = blockIdx.x >> 1, h = blockIdx.x & 1;  // token grp, code half
  const int col = lane & 15, kq = lane >> 4;
  const int tw = tb * 128 + w * 32;  // this wave's 32 tokens

  // prologue: x -> registers in A-fragment layout; xsq (half 0 only)
  f16x8 a[2][8];
  float sqm[2] = {0.f, 0.f};
#pragma unroll
  for (int m = 0; m < 2; ++m) {
#pragma unroll
    for (int s = 0; s < 8; ++s) {
      const float* xp = &x[(tw + m * 16 + col) * DIM + s * 32 + kq * 8];
      const float4 v0 = *reinterpret_cast<const float4*>(xp);
      const float4 v1 = *reinterpret_cast<const float4*>(xp + 4);
      a[m][s][0] = (_Float16)v0.x; a[m][s][1] = (_Float16)v0.y;
      a[m][s][2] = (_Float16)v0.z; a[m][s][3] = (_Float16)v0.w;
      a[m][s][4] = (_Float16)v1.x; a[m][s][5] = (_Float16)v1.y;
      a[m][s][6] = (_Float16)v1.z; a[m][s][7] = (_Float16)v1.w;
      sqm[m] += v0.x * v0.x + v0.y * v0.y + v0.z * v0.z + v0.w * v0.w +
                v1.x * v1.x + v1.y * v1.y + v1.z * v1.z + v1.w * v1.w;
    }
  }
  if (h == 0) {
#pragma unroll
    for (int m = 0; m < 2; ++m) {
      sqm[m] += __shfl_xor(sqm[m], 16, 64);
      sqm[m] += __shfl_xor(sqm[m], 32, 64);
    }
    if (lane < 16) {
      xsq[tw + lane] = sqm[0];
      xsq[tw + 16 + lane] = sqm[1];
    }
  }

  float best[2][4], second[2][4];
  int bidx[2][4];
#pragma unroll
  for (int mi = 0; mi < 2; ++mi)
#pragma unroll
    for (int r = 0; r < 4; ++r) {
      best[mi][r] = 3.4e38f; second[mi][r] = 3.4e38f; bidx[mi][r] = 0;
    }

  for (int c = 0; c < 4; ++c) {
    const int ct = h * 4 + c;
    const char* ebase = (const char*)eg + ct * 65536;
    f32x4 acc[2][8];
#pragma unroll
    for (int mi = 0; mi < 2; ++mi)
#pragma unroll
      for (int nj = 0; nj < 8; ++nj) acc[mi][nj] = (f32x4){0.f, 0.f, 0.f, 0.f};

#pragma unroll
    for (int s = 0; s < 8; ++s) {
      f16x8 b[8];
#pragma unroll
      for (int nj = 0; nj < 8; ++nj)
        b[nj] = *reinterpret_cast<const f16x8*>(
            ebase + ((s * 8 + nj) << 10) + (lane << 4));
#pragma unroll
      for (int mi = 0; mi < 2; ++mi)
#pragma unroll
        for (int nj = 0; nj < 8; ++nj)
          acc[mi][nj] = __builtin_amdgcn_mfma_f32_16x16x32_f16(
              a[mi][s], b[nj], acc[mi][nj], 0, 0, 0);
    }

    // distances; codes ascend per lane over (c, nj) -> strict < = first min
#pragma unroll
    for (int nj = 0; nj < 8; ++nj) {
      const int code = ct * 128 + nj * 16 + col;
      const float sqv = esq[code];
#pragma unroll
      for (int mi = 0; mi < 2; ++mi)
#pragma unroll
        for (int r = 0; r < 4; ++r) {
          const float d = fmaf(-2.f, acc[mi][nj][r], sqv);
          if (d < best[mi][r]) {
            second[mi][r] = best[mi][r];
            best[mi][r] = d;
            bidx[mi][r] = code;
          } else if (d < second[mi][r]) {
            second[mi][r] = d;
          }
        }
    }
  }

  // wave-local cross-lane reduce over the 16 code-columns
#pragma unroll
  for (int mi = 0; mi < 2; ++mi)
#pragma unroll
    for (int r = 0; r < 4; ++r) {
      float b = best[mi][r], s2 = second[mi][r];
      int bi = bidx[mi][r];
#pragma unroll
      for (int m = 1; m <= 8; m <<= 1) {
        const float ob = __shfl_xor(b, m, 64);
        const float os = __shfl_xor(s2, m, 64);
        const int   oi = __shfl_xor(bi, m, 64);
        s2 = fminf(fminf(s2, os), fmaxf(b, ob));
        if (ob < b || (ob == b && oi < bi)) { b = ob; bi = oi; }
      }
      if (col == 0) {
        const int t = tw + mi * 16 + kq * 4 + r;
        const unsigned flag = (s2 - b < EPS) ? 0x80000000u : 0u;
        bH[h * NTOK + t] = b;
        iH[h * NTOK + t] = (unsigned)bi | flag;
      }
    }
}

// ---- merge halves + hist + fixList + loss partials + gather ----
__global__ __launch_bounds__(256) void vq_finish(
    const float* __restrict__ e, const float* __restrict__ bH,
    const unsigned int* __restrict__ iH, const float* __restrict__ xsq,
    float* __restrict__ outIdxF, float* __restrict__ outQ,
    int* __restrict__ hist, int* __restrict__ fixCount,
    int* __restrict__ fixList, float* __restrict__ partial) {
  const int tid = threadIdx.x, lane = tid & 63, w = tid >> 6;
  const int t = blockIdx.x * 4 + w;
  const float b0 = bH[t], b1 = bH[NTOK + t];
  const unsigned ii0 = iH[t], ii1 = iH[NTOK + t];
  int ic; float bc;
  if (b1 < b0) { bc = b1; ic = (int)(ii1 & 0x7FFFFFFFu); }
  else         { bc = b0; ic = (int)(ii0 & 0x7FFFFFFFu); }  // tie -> half 0 (lower idx)
  __shared__ float ls[4];
  if (lane == 0) {
    outIdxF[t] = (float)ic;
    atomicAdd(&hist[ic], 1);
    const bool flag = (((ii0 | ii1) >> 31) != 0u) || (fabsf(b0 - b1) < EPS);
    if (flag) fixList[atomicAdd(fixCount, 1)] = t;
    ls[w] = xsq[t] + bc;
  }
  const float4 q = reinterpret_cast<const float4*>(&e[ic * DIM])[lane];
  reinterpret_cast<float4*>(&outQ[t * DIM])[lane] = q;
  __syncthreads();
  if (tid == 0) partial[blockIdx.x] = ls[0] + ls[1] + ls[2] + ls[3];
}

// ---- exact fp32 rescan for near-tie tokens; patch idx/hist/outQ/loss ----
__global__ __launch_bounds__(256) void vq_fixup(
    const float* __restrict__ x, const float* __restrict__ e,
    const float* __restrict__ esq, const int* __restrict__ fixCount,
    const int* __restrict__ fixList, const float* __restrict__ bH,
    float* __restrict__ outIdxF, float* __restrict__ outQ,
    int* __restrict__ hist, float* __restrict__ lossCorr) {
  const int n = *fixCount;
  __shared__ float xrow[256];
  __shared__ float rv[4];
  __shared__ int ri[4];
  __shared__ int sOld, sFi;
  const int tid = threadIdx.x;
  for (int it = blockIdx.x; it < n; it += gridDim.x) {
    const int t = fixList[it];
    __syncthreads();
    if (tid < 64) ((float4*)xrow)[tid] = ((const float4*)&x[t * DIM])[tid];
    __syncthreads();
    float bv = 3.4e38f; int bi = 0;
    for (int c = tid; c < KC; c += 256) {
      float s = 0.f;
#pragma unroll
      for (int d = 0; d < DIM; d += 4) {
        const float4 ev = *(const float4*)&e[c * DIM + d];
        s = fmaf(xrow[d], ev.x, s);
        s = fmaf(xrow[d + 1], ev.y, s);
        s = fmaf(xrow[d + 2], ev.z, s);
        s = fmaf(xrow[d + 3], ev.w, s);
      }
      const float dist = fmaf(-2.f, s, esq[c]);
      if (dist < bv) { bv = dist; bi = c; }  // c ascends per thread
    }
#pragma unroll
    for (int m = 1; m <= 32; m <<= 1) {
      const float ob = __shfl_xor(bv, m, 64);
      const int oi = __shfl_xor(bi, m, 64);
      if (ob < bv || (ob == bv && oi < bi)) { bv = ob; bi = oi; }
    }
    const int lane = tid & 63, wv = tid >> 6;
    if (lane == 0) { rv[wv] = bv; ri[wv] = bi; }
    __syncthreads();
    if (tid == 0) {
      float fb = rv[0]; int fi = ri[0];
      for (int k = 1; k < 4; ++k)
        if (rv[k] < fb || (rv[k] == fb && ri[k] < fi)) { fb = rv[k]; fi = ri[k]; }
      const float oldb = fminf(bH[t], bH[NTOK + t]);
      atomicAdd(lossCorr, fb - oldb);  // exact-distance correction
      sOld = (int)outIdxF[t];
      sFi = fi;
      if (fi != sOld) {
        atomicSub(&hist[sOld], 1);
        atomicAdd(&hist[fi], 1);
        outIdxF[t] = (float)fi;
      }
    }
    __syncthreads();
    if (sFi != sOld) outQ[t * DIM + tid] = e[sFi * DIM + tid];
    __syncthreads();
  }
}

// ---- final scalars ----
__global__ __launch_bounds__(1024) void vq_final(
    const int* __restrict__ hist, const float* __restrict__ partial,
    const float* __restrict__ lossCorr, float* __restrict__ outLoss,
    float* __restrict__ outPerp) {
  const int tid = threadIdx.x;
  float ls = 0.f;
#pragma unroll
  for (int i = 0; i < 16; ++i) ls += partial[tid + i * 1024];
  const float p = (float)hist[tid] * (1.f / 65536.f);
  float ent = p * logf(p + 1e-10f);
#pragma unroll
  for (int o = 32; o > 0; o >>= 1) {
    ls += __shfl_down(ls, o, 64);
    ent += __shfl_down(ent, o, 64);
  }
  __shared__ float lbuf[16], ebuf[16];
  const int lane = tid & 63, wv = tid >> 6;
  if (lane == 0) { lbuf[wv] = ls; ebuf[wv] = ent; }
  __syncthreads();
  if (tid == 0) {
    float L = 0.f, E = 0.f;
    for (int i = 0; i < 16; ++i) { L += lbuf[i]; E += ebuf[i]; }
    *outLoss = 0.25f * ((L + *lossCorr) / 16777216.f);
    *outPerp = expf(-E);
  }
}

extern "C" void kernel_launch(void* const* d_in, const int* in_sizes, int n_in,
                              void* d_out, int out_size, void* d_ws, size_t ws_size,
                              hipStream_t stream) {
  const float* x = (const float*)d_in[0];  // [65536, 256]
  const float* e = (const float*)d_in[1];  // [1024, 256]
  float* out = (float*)d_out;
  float* outQ = out;                 // 16777216 floats
  float* outLoss = out + 16777216;
  float* outPerp = out + 16777217;
  float* outIdxF = out + 16777218;   // 65536 floats

  char* ws = (char*)d_ws;
  int*   hist     = (int*)ws;                     // 4 KB
  float* esq      = (float*)(ws + 4096);          // 4 KB
  float* xsq      = (float*)(ws + 8192);          // 256 KB
  int*   fixList  = (int*)(ws + 270336);          // 256 KB
  int*   fixCount = (int*)(ws + 532480);          // 4 B
  float* lossCorr = (float*)(ws + 532484);        // 4 B
  float* partial  = (float*)(ws + 532496);        // 64 KB (16384 f)
  float* bH       = (float*)(ws + 598032);        // 512 KB (2 x NTOK)
  unsigned int* iH = (unsigned int*)(ws + 1122320);  // 512 KB
  unsigned short* e_f16 = (unsigned short*)(ws + 1646608);  // 512 KB
  // total ws use ~2.07 MB

  vq_prep_e<<<128, 256, 0, stream>>>(e, e_f16, esq, hist, fixCount, lossCorr);
  vq_argmin<<<1024, 256, 0, stream>>>(x, e_f16, esq, bH, iH, xsq);
  vq_finish<<<NTOK / 4, 256, 0, stream>>>(e, bH, iH, xsq, outIdxF, outQ, hist,
                                          fixCount, fixList, partial);
  vq_fixup<<<256, 256, 0, stream>>>(x, e, esq, fixCount, fixList, bH, outIdxF,
                                    outQ, hist, lossCorr);
  vq_final<<<1, 1024, 0, stream>>>(hist, partial, lossCorr, outLoss, outPerp);
}

// Round 8
// 189.849 us; speedup vs baseline: 2.1726x; 2.1726x over previous
//
#include <hip/hip_runtime.h>

#define NTOK 65536
#define DIM 256
#define KC 1024
#define EPS 0.08f

typedef __attribute__((ext_vector_type(8))) _Float16 f16x8;
typedef __attribute__((ext_vector_type(8))) unsigned short u16x8;
typedef __attribute__((ext_vector_type(4))) float f32x4;

static __device__ __forceinline__ unsigned short f16bits(float f) {
  _Float16 h = (_Float16)f;
  return __builtin_bit_cast(unsigned short, h);
}

// ---- e: fp32 -> fp16 FRAGMENT-MAJOR global image + esq; zero scalars ----
// Chunk c = ct*64 + s*8 + nj (1 KB each): lane = kq*16+col holds
// e[ct*128 + nj*16 + col][s*32 + kq*8 + j], j=0..7, as 8 f16.
__global__ __launch_bounds__(256) void vq_prep_e(const float* __restrict__ e,
                                                 unsigned short* __restrict__ eg,
                                                 float* __restrict__ esq,
                                                 int* __restrict__ hist,
                                                 int* __restrict__ fixCount) {
  const int gid = blockIdx.x * 256 + threadIdx.x;  // 32768 work items
  const int t = gid >> 5;   // code row 0..1023
  const int o = gid & 31;   // k-octet 0..31
  const float4 v0 = *reinterpret_cast<const float4*>(&e[t * DIM + o * 8]);
  const float4 v1 = *reinterpret_cast<const float4*>(&e[t * DIM + o * 8 + 4]);
  u16x8 u;
  u[0] = f16bits(v0.x); u[1] = f16bits(v0.y); u[2] = f16bits(v0.z); u[3] = f16bits(v0.w);
  u[4] = f16bits(v1.x); u[5] = f16bits(v1.y); u[6] = f16bits(v1.z); u[7] = f16bits(v1.w);
  const int ct = t >> 7, nj = (t >> 4) & 7, col = t & 15;
  const int s = o >> 2, kq = o & 3;
  char* dst = (char*)eg + ((ct * 64 + s * 8 + nj) << 10) + ((kq * 16 + col) << 4);
  *reinterpret_cast<u16x8*>(dst) = u;
  float p = v0.x * v0.x + v0.y * v0.y + v0.z * v0.z + v0.w * v0.w +
            v1.x * v1.x + v1.y * v1.y + v1.z * v1.z + v1.w * v1.w;
#pragma unroll
  for (int m = 16; m > 0; m >>= 1) p += __shfl_xor(p, m, 64);
  if (o == 0) esq[t] = p;
  if (blockIdx.x < 4) hist[blockIdx.x * 256 + threadIdx.x] = 0;
  if (gid == 0) *fixCount = 0;
}

// ---- 1-wave blocks: 16 tokens x full 1024 codes, top-3 tracking ----
__global__ __launch_bounds__(64, 4) void vq_argmin(
    const float* __restrict__ x, const unsigned short* __restrict__ eg,
    const float* __restrict__ esq, const float* __restrict__ e,
    float* __restrict__ outIdxF, float* __restrict__ outQ,
    float* __restrict__ bestDist, float* __restrict__ xsq,
    int* __restrict__ hist, int* __restrict__ fixCount,
    unsigned int* __restrict__ fixList) {
  const int lane = threadIdx.x;
  const int col = lane & 15, kq = lane >> 4;
  const int tw = blockIdx.x * 16;  // 16 tokens per wave

  // prologue: x -> A-fragments (lane holds token tw+col, k = s*32+kq*8+j)
  f16x8 a[8];
  float sq = 0.f;
#pragma unroll
  for (int s = 0; s < 8; ++s) {
    const float* xp = &x[(tw + col) * DIM + s * 32 + kq * 8];
    const float4 v0 = *reinterpret_cast<const float4*>(xp);
    const float4 v1 = *reinterpret_cast<const float4*>(xp + 4);
    a[s][0] = (_Float16)v0.x; a[s][1] = (_Float16)v0.y;
    a[s][2] = (_Float16)v0.z; a[s][3] = (_Float16)v0.w;
    a[s][4] = (_Float16)v1.x; a[s][5] = (_Float16)v1.y;
    a[s][6] = (_Float16)v1.z; a[s][7] = (_Float16)v1.w;
    sq += v0.x * v0.x + v0.y * v0.y + v0.z * v0.z + v0.w * v0.w +
          v1.x * v1.x + v1.y * v1.y + v1.z * v1.z + v1.w * v1.w;
  }
  sq += __shfl_xor(sq, 16, 64);
  sq += __shfl_xor(sq, 32, 64);
  if (lane < 16) xsq[tw + lane] = sq;

  // per-lane top-3 (values) + top-2 indices, per accumulator row r
  float v1_[4], v2_[4], v3_[4];
  int i1_[4], i2_[4];
#pragma unroll
  for (int r = 0; r < 4; ++r) {
    v1_[r] = 3.4e38f; v2_[r] = 3.4e38f; v3_[r] = 3.4e38f;
    i1_[r] = 0; i2_[r] = 0;
  }

  for (int ct = 0; ct < 8; ++ct) {
    const char* ebase = (const char*)eg + ct * 65536;
    f32x4 acc[8];
#pragma unroll
    for (int nj = 0; nj < 8; ++nj) acc[nj] = (f32x4){0.f, 0.f, 0.f, 0.f};

#pragma unroll
    for (int s = 0; s < 8; ++s) {
      f16x8 b[8];
#pragma unroll
      for (int nj = 0; nj < 8; ++nj)
        b[nj] = *reinterpret_cast<const f16x8*>(
            ebase + ((s * 8 + nj) << 10) + (lane << 4));
#pragma unroll
      for (int nj = 0; nj < 8; ++nj)
        acc[nj] = __builtin_amdgcn_mfma_f32_16x16x32_f16(a[s], b[nj], acc[nj], 0, 0, 0);
    }

    // distances; codes ascend per lane over (ct, nj) -> strict < = first min
#pragma unroll
    for (int nj = 0; nj < 8; ++nj) {
      const int code = ct * 128 + nj * 16 + col;
      const float sqv = esq[code];
#pragma unroll
      for (int r = 0; r < 4; ++r) {
        const float d = fmaf(-2.f, acc[nj][r], sqv);
        if (d < v1_[r]) {
          v3_[r] = v2_[r]; v2_[r] = v1_[r]; i2_[r] = i1_[r];
          v1_[r] = d; i1_[r] = code;
        } else if (d < v2_[r]) {
          v3_[r] = v2_[r]; v2_[r] = d; i2_[r] = code;
        } else if (d < v3_[r]) {
          v3_[r] = d;
        }
      }
    }
  }

  // cross-lane top-3 merge over the 16 code-columns (masks 1,2,4,8)
#pragma unroll
  for (int r = 0; r < 4; ++r) {
    float mv1 = v1_[r], mv2 = v2_[r], mv3 = v3_[r];
    int mi1 = i1_[r], mi2 = i2_[r];
#pragma unroll
    for (int m = 1; m <= 8; m <<= 1) {
      const float ov1 = __shfl_xor(mv1, m, 64);
      const float ov2 = __shfl_xor(mv2, m, 64);
      const float ov3 = __shfl_xor(mv3, m, 64);
      const int oi1 = __shfl_xor(mi1, m, 64);
      const int oi2 = __shfl_xor(mi2, m, 64);
      const bool oW = (ov1 < mv1) || (ov1 == mv1 && oi1 < mi1);
      const float wv1 = oW ? ov1 : mv1, wv2 = oW ? ov2 : mv2, wv3 = oW ? ov3 : mv3;
      const int wi1 = oW ? oi1 : mi1, wi2 = oW ? oi2 : mi2;
      const float lv1 = oW ? mv1 : ov1, lv2 = oW ? mv2 : ov2;
      const int li1 = oW ? mi1 : oi1;
      const bool w2 = (wv2 < lv1) || (wv2 == lv1 && wi2 < li1);
      mv1 = wv1; mi1 = wi1;
      mv2 = w2 ? wv2 : lv1;
      mi2 = w2 ? wi2 : li1;
      mv3 = w2 ? fminf(wv3, lv1) : fminf(wv2, lv2);
    }
    if (col == 0) {
      const int t = tw + kq * 4 + r;
      outIdxF[t] = (float)mi1;
      bestDist[t] = mv1;
      atomicAdd(&hist[mi1], 1);
      if (mv2 - mv1 < EPS) {
        const unsigned full = (mv3 - mv1 < EPS) ? 0x80000000u : 0u;
        const int p = atomicAdd(fixCount, 1);
        fixList[p * 2] = (unsigned)t | full;
        fixList[p * 2 + 1] = (unsigned)mi2;
      }
    }
    i1_[r] = mi1;  // merged result, identical on all 16 lanes of the kq group
  }

  // fused gather: 16 tokens, index broadcast via shfl (no LDS, no barrier)
#pragma unroll
  for (int i = 0; i < 16; ++i) {
    const int id = __shfl(i1_[i & 3], (i >> 2) * 16, 64);
    const float4 q = reinterpret_cast<const float4*>(&e[id * DIM])[lane];
    reinterpret_cast<float4*>(&outQ[(tw + i) * DIM])[lane] = q;
  }
}

// ---- fixup: pairwise exact check (common) or full rescan (rare) ----
__global__ __launch_bounds__(256) void vq_fixup(
    const float* __restrict__ x, const float* __restrict__ e,
    const int* __restrict__ fixCount, const unsigned int* __restrict__ fixList,
    float* __restrict__ outIdxF, float* __restrict__ outQ,
    float* __restrict__ bestDist, int* __restrict__ hist) {
  const int n = *fixCount;
  const int tid = threadIdx.x;
  __shared__ float xrow[256];
  __shared__ float rv[4];
  __shared__ int ri[4];
  __shared__ int sOld, sFi;
  for (int it = blockIdx.x; it < n; it += gridDim.x) {
    const unsigned e0 = fixList[it * 2];
    const int t = (int)(e0 & 0x3FFFFFFFu);
    const bool full = (e0 >> 31) != 0u;
    if (!full) {
      // pairwise: wave 0 exactly compares rows i1 (current) and i2
      if (tid < 64) {
        const int i1 = (int)outIdxF[t];
        const int i2 = (int)fixList[it * 2 + 1];
        const float4 xv = reinterpret_cast<const float4*>(&x[t * DIM])[tid];
        const float4 e1 = reinterpret_cast<const float4*>(&e[i1 * DIM])[tid];
        const float4 e2 = reinterpret_cast<const float4*>(&e[i2 * DIM])[tid];
        float d1 = (xv.x - e1.x) * (xv.x - e1.x) + (xv.y - e1.y) * (xv.y - e1.y) +
                   (xv.z - e1.z) * (xv.z - e1.z) + (xv.w - e1.w) * (xv.w - e1.w);
        float d2 = (xv.x - e2.x) * (xv.x - e2.x) + (xv.y - e2.y) * (xv.y - e2.y) +
                   (xv.z - e2.z) * (xv.z - e2.z) + (xv.w - e2.w) * (xv.w - e2.w);
#pragma unroll
        for (int m = 32; m > 0; m >>= 1) {
          d1 += __shfl_xor(d1, m, 64);
          d2 += __shfl_xor(d2, m, 64);
        }
        const bool swap2 = (d2 < d1) || (d2 == d1 && i2 < i1);
        const int wIdx = swap2 ? i2 : i1;
        const float wD = swap2 ? d2 : d1;
        if (tid == 0) {
          bestDist[t] = wD;
          if (wIdx != i1) {
            atomicSub(&hist[i1], 1);
            atomicAdd(&hist[wIdx], 1);
            outIdxF[t] = (float)wIdx;
          }
        }
        if (swap2) {
          const float4 q = reinterpret_cast<const float4*>(&e[wIdx * DIM])[tid];
          reinterpret_cast<float4*>(&outQ[t * DIM])[tid] = q;
        }
      }
    } else {
      // full exact rescan (expected ~1-3 tokens total)
      __syncthreads();
      if (tid < 64) ((float4*)xrow)[tid] = ((const float4*)&x[t * DIM])[tid];
      __syncthreads();
      float bv = 3.4e38f; int bi = 0;
      for (int c = tid; c < KC; c += 256) {
        float s = 0.f;
#pragma unroll
        for (int d = 0; d < DIM; d += 4) {
          const float4 ev = *(const float4*)&e[c * DIM + d];
          const float d0 = xrow[d] - ev.x, d1 = xrow[d + 1] - ev.y;
          const float d2 = xrow[d + 2] - ev.z, d3 = xrow[d + 3] - ev.w;
          s += d0 * d0 + d1 * d1 + d2 * d2 + d3 * d3;
        }
        if (s < bv) { bv = s; bi = c; }  // c ascends per thread
      }
#pragma unroll
      for (int m = 1; m <= 32; m <<= 1) {
        const float ob = __shfl_xor(bv, m, 64);
        const int oi = __shfl_xor(bi, m, 64);
        if (ob < bv || (ob == bv && oi < bi)) { bv = ob; bi = oi; }
      }
      const int lane = tid & 63, wv = tid >> 6;
      if (lane == 0) { rv[wv] = bv; ri[wv] = bi; }
      __syncthreads();
      if (tid == 0) {
        float fb = rv[0]; int fi = ri[0];
        for (int k = 1; k < 4; ++k)
          if (rv[k] < fb || (rv[k] == fb && ri[k] < fi)) { fb = rv[k]; fi = ri[k]; }
        sOld = (int)outIdxF[t];
        sFi = fi;
        bestDist[t] = fb;
        if (fi != sOld) {
          atomicSub(&hist[sOld], 1);
          atomicAdd(&hist[fi], 1);
          outIdxF[t] = (float)fi;
        }
      }
      __syncthreads();
      if (sFi != sOld) outQ[t * DIM + tid] = e[sFi * DIM + tid];
      __syncthreads();
    }
  }
}

// ---- final scalars: loss from xsq+bestDist; perplexity from hist ----
__global__ __launch_bounds__(1024) void vq_final(
    const int* __restrict__ hist, const float* __restrict__ xsq,
    const float* __restrict__ bestDist, float* __restrict__ outLoss,
    float* __restrict__ outPerp) {
  const int tid = threadIdx.x;
  float ls = 0.f;
  for (int i = 0; i < 64; ++i) {
    const int t = tid + i * 1024;
    ls += xsq[t] + bestDist[t];
  }
  const float p = (float)hist[tid] * (1.f / 65536.f);
  float ent = p * logf(p + 1e-10f);
#pragma unroll
  for (int o = 32; o > 0; o >>= 1) {
    ls += __shfl_down(ls, o, 64);
    ent += __shfl_down(ent, o, 64);
  }
  __shared__ float lbuf[16], ebuf[16];
  const int lane = tid & 63, wv = tid >> 6;
  if (lane == 0) { lbuf[wv] = ls; ebuf[wv] = ent; }
  __syncthreads();
  if (tid == 0) {
    float L = 0.f, E = 0.f;
    for (int i = 0; i < 16; ++i) { L += lbuf[i]; E += ebuf[i]; }
    *outLoss = 0.25f * (L / 16777216.f);
    *outPerp = expf(-E);
  }
}

extern "C" void kernel_launch(void* const* d_in, const int* in_sizes, int n_in,
                              void* d_out, int out_size, void* d_ws, size_t ws_size,
                              hipStream_t stream) {
  const float* x = (const float*)d_in[0];  // [65536, 256]
  const float* e = (const float*)d_in[1];  // [1024, 256]
  float* out = (float*)d_out;
  float* outQ = out;                 // 16777216 floats
  float* outLoss = out + 16777216;
  float* outPerp = out + 16777217;
  float* outIdxF = out + 16777218;   // 65536 floats

  char* ws = (char*)d_ws;
  int*   hist     = (int*)ws;                     // 4 KB
  float* esq      = (float*)(ws + 4096);          // 4 KB
  float* xsq      = (float*)(ws + 8192);          // 256 KB
  float* bestDist = (float*)(ws + 270336);        // 256 KB
  int*   fixCount = (int*)(ws + 532480);          // 16 B
  unsigned int* fixList = (unsigned int*)(ws + 532496);  // 512 KB (2/entry)
  unsigned short* e_f16 = (unsigned short*)(ws + 1056784);  // 512 KB
  // total ws use ~1.57 MB

  vq_prep_e<<<128, 256, 0, stream>>>(e, e_f16, esq, hist, fixCount);
  vq_argmin<<<NTOK / 16, 64, 0, stream>>>(x, e_f16, esq, e, outIdxF, outQ,
                                          bestDist, xsq, hist, fixCount, fixList);
  vq_fixup<<<256, 256, 0, stream>>>(x, e, fixCount, fixList, outIdxF, outQ,
                                    bestDist, hist);
  vq_final<<<1, 1024, 0, stream>>>(hist, xsq, bestDist, outLoss, outPerp);
}